// Round 2
// baseline (313.782 us; speedup 1.0000x reference)
//
#include <hip/hip_runtime.h>

// out[b,i,d] = x[b,i,0] * W[i,d] + b[i,d];  B=128, N=1024, D=512, fp32.
//
// v2 (resubmit — round 1 failed on container acquisition, no data):
// Previous kernel (wave = 1 row x 8 batches) issued 16 x 2 KiB stores into 8
// regions 512 KiB apart; with ~2048 resident waves that is ~65K scattered
// 2-KiB chunks in flight -> HBM write-locality collapse (~2.7 TB/s effective
// vs 6.4 TB/s measured same-run by the harness's own 1-GiB fill kernel).
// This version makes each wave write ONE linear 128-KiB stream (fill-like):
// wave = (batch b, 64-row span), rows streamed in address order. W/bias are
// re-read per batch but stay L2-resident (4 MiB combined; ~512 MB aggregate
// L2 reads ~ 11 TB/s << 34.5 TB/s L2 ceiling); x is preloaded one-per-lane
// and broadcast via __shfl. NT stores kept (protect W/bias L2 residency) —
// single structural change vs round 0 so the post-mortem is unambiguous.

constexpr int kN    = 1024;
constexpr int kD4   = 512 / 4;   // 128 float4 per row
constexpr int kRows = 64;        // rows per wave -> 128 KiB contiguous/wave

typedef float v4f __attribute__((ext_vector_type(4)));

__global__ __launch_bounds__(256) void bcast_fma_kernel(
    const float* __restrict__ x,       // [B*N]
    const v4f*   __restrict__ W,       // [N*D4]
    const v4f*   __restrict__ bias,    // [N*D4]
    v4f*         __restrict__ out)     // [B*N*D4]
{
    const int wave = threadIdx.x >> 6;
    const int lane = threadIdx.x & 63;
    const int w    = (blockIdx.x << 2) + wave;   // wave id, 0..2047
    const int b    = w >> 4;                     // batch 0..127
    const int i0   = (w & 15) * kRows;           // row-span start

    // lane l holds x[b, i0+l]; broadcast per-row below via __shfl.
    const float xl = x[b * kN + i0 + lane];

    const int  wb = i0 * kD4 + lane;
    const long ob = (long)b * (kN * kD4) + wb;

#pragma unroll 4
    for (int r = 0; r < kRows; ++r) {
        const float xr = __shfl(xl, r, 64);
        const int   o  = r * kD4;
        const v4f w0 = W[wb + o];
        const v4f w1 = W[wb + o + 64];
        const v4f c0 = bias[wb + o];
        const v4f c1 = bias[wb + o + 64];
        v4f o0, o1;
        o0.x = fmaf(xr, w0.x, c0.x);
        o0.y = fmaf(xr, w0.y, c0.y);
        o0.z = fmaf(xr, w0.z, c0.z);
        o0.w = fmaf(xr, w0.w, c0.w);
        o1.x = fmaf(xr, w1.x, c1.x);
        o1.y = fmaf(xr, w1.y, c1.y);
        o1.z = fmaf(xr, w1.z, c1.z);
        o1.w = fmaf(xr, w1.w, c1.w);
        __builtin_nontemporal_store(o0, &out[ob + o]);
        __builtin_nontemporal_store(o1, &out[ob + o + 64]);
    }
}

extern "C" void kernel_launch(void* const* d_in, const int* in_sizes, int n_in,
                              void* d_out, int out_size, void* d_ws, size_t ws_size,
                              hipStream_t stream) {
    const float* x    = (const float*)d_in[0];
    const v4f*   W    = (const v4f*)d_in[1];
    const v4f*   bias = (const v4f*)d_in[2];
    v4f*         out  = (v4f*)d_out;

    constexpr int kWaves = 128 * (kN / kRows);   // 2048 waves
    constexpr int kGrid  = kWaves / 4;           // 512 blocks of 256 threads
    bcast_fma_kernel<<<kGrid, 256, 0, stream>>>(x, W, bias, out);
}

// Round 3
// 262.737 us; speedup vs baseline: 1.1943x; 1.1943x over previous
//
#include <hip/hip_runtime.h>

// out[b,i,d] = x[b,i,0] * W[i,d] + b[i,d];  B=128, N=1024, D=512, fp32.
//
// v3: exact baseline structure (269 us: wave owns row i for 8 consecutive
// batches; W/bias row read ONCE into 16 VGPRs; 16 x 1-KiB float4 stores per
// wave) with ONE change: plain stores instead of __builtin_nontemporal_store.
//
// Rationale: harness fill kernel (plain stores) sustains one 1-KiB store per
// ~98 cyc/CU (6.4 TB/s) at ~3 waves/CU; baseline-NT ran at 233 cyc/store
// (2.7 TB/s). NT = no-allocate: bypasses L2/L3 write buffering, so HBM sees
// the raw arrival order -- 65K interleaved 2-KiB chunks over 256 MB -> row
// thrash. Plain stores let L2 (32 MB) + L3 (256 MB, ~fits the whole 268 MB
// output) absorb and reorder into locality-friendly writebacks. The original
// NT rationale (protect W/bias L2 residency) is moot in the read-once
// structure. v2 lesson folded in: never re-read W/bias per iteration.

constexpr int kB   = 128;
constexpr int kN   = 1024;
constexpr int kD4  = 512 / 4;            // 128 float4 per row
constexpr int kBG  = 8;                  // batches per wave
constexpr int kRowStride4 = kN * kD4;    // float4 stride between batches

typedef float v4f __attribute__((ext_vector_type(4)));

__global__ __launch_bounds__(256) void bcast_fma_kernel(
    const float* __restrict__ x,       // [B*N]
    const v4f*   __restrict__ W,       // [N*D4]
    const v4f*   __restrict__ bias,    // [N*D4]
    v4f*         __restrict__ out)     // [B*N*D4]
{
    const int wave = threadIdx.x >> 6;              // 0..3
    const int lane = threadIdx.x & 63;
    const int w    = (blockIdx.x << 2) + wave;      // wave id, < kN * (kB/kBG)
    const int i    = w & (kN - 1);                  // row index
    const int bg   = w >> 10;                       // batch group, 0..15

    const int wb = i * kD4;
    const v4f w0 = W[wb + lane];
    const v4f w1 = W[wb + lane + 64];
    const v4f b0 = bias[wb + lane];
    const v4f b1 = bias[wb + lane + 64];

    // Wave-uniform x values for the 8 batches (issued up-front for ILP).
    float xv[kBG];
#pragma unroll
    for (int g = 0; g < kBG; ++g)
        xv[g] = x[(bg * kBG + g) * kN + i];

    // Output base for batch bg*kBG, row i.
    const long ob = (long)(bg * kBG) * kRowStride4 + (long)i * kD4 + lane;

#pragma unroll
    for (int g = 0; g < kBG; ++g) {
        const float xg = xv[g];
        v4f o0, o1;
        o0.x = fmaf(xg, w0.x, b0.x);
        o0.y = fmaf(xg, w0.y, b0.y);
        o0.z = fmaf(xg, w0.z, b0.z);
        o0.w = fmaf(xg, w0.w, b0.w);
        o1.x = fmaf(xg, w1.x, b1.x);
        o1.y = fmaf(xg, w1.y, b1.y);
        o1.z = fmaf(xg, w1.z, b1.z);
        o1.w = fmaf(xg, w1.w, b1.w);
        out[ob + (long)g * kRowStride4]      = o0;   // plain store (was NT)
        out[ob + (long)g * kRowStride4 + 64] = o1;   // plain store (was NT)
    }
}

extern "C" void kernel_launch(void* const* d_in, const int* in_sizes, int n_in,
                              void* d_out, int out_size, void* d_ws, size_t ws_size,
                              hipStream_t stream) {
    const float* x    = (const float*)d_in[0];
    const v4f*   W    = (const v4f*)d_in[1];
    const v4f*   bias = (const v4f*)d_in[2];
    v4f*         out  = (v4f*)d_out;

    constexpr int kWaves = kN * (kB / kBG);        // 16384
    constexpr int kGrid  = kWaves / 4;             // 4096 blocks of 256
    bcast_fma_kernel<<<kGrid, 256, 0, stream>>>(x, W, bias, out);
}